// Round 20
// baseline (70.205 us; speedup 1.0000x reference)
//
#include <hip/hip_runtime.h>
#include <math.h>

#define E_DIM 1024
#define H_DIM 64
#define S_LEN 4096
#define B_SZ  4

typedef short s16x8 __attribute__((ext_vector_type(8)));
typedef short s16x4 __attribute__((ext_vector_type(4)));
typedef float f32x4 __attribute__((ext_vector_type(4)));
typedef unsigned short u16;
typedef unsigned int u32;

// q is pre-scaled by 1/sqrt(H) * log2(e) so attention uses exp2 throughout.
#define QSCALE 0.180336880f
#define CHUNK  512
#define MAXC   8      // S_LEN / CHUNK
#define KB     64     // keys per staged LDS tile (attention)

static __device__ __forceinline__ u16 f2b(float f) {
    u32 u = __builtin_bit_cast(u32, f);
    u += 0x7fffu + ((u >> 16) & 1u);        // RNE
    return (u16)(u >> 16);
}
static __device__ __forceinline__ u32 pk2(float lo, float hi) {
    return (u32)f2b(lo) | ((u32)f2b(hi) << 16);
}
// fp16 pack/unpack for attn split-K partials (|O_part| <~ 3e3 << 65504;
// post-division error ~2e-3 << 0.079 threshold).
static __device__ __forceinline__ u32 pkh2(float a, float b) {
    _Float16 ha = (_Float16)a, hb = (_Float16)b;
    return (u32)__builtin_bit_cast(u16, ha) | ((u32)__builtin_bit_cast(u16, hb) << 16);
}
static __device__ __forceinline__ float h2f(u16 u) {
    return (float)__builtin_bit_cast(_Float16, u);
}

// async global->LDS, 16B per lane; LDS dest = wave-uniform base + lane*16,
// global source is per-lane.
static __device__ __forceinline__ void gload16(const void* g, void* l) {
    __builtin_amdgcn_global_load_lds(
        (const __attribute__((address_space(1))) u32*)g,
        (__attribute__((address_space(3))) u32*)l, 16, 0, 0);
}

#if defined(__has_builtin)
#  if __has_builtin(__builtin_amdgcn_mfma_f32_16x16x16bf16_1k)
#    define USE_1K 1
#  else
#    define USE_1K 0
#  endif
#else
#  define USE_1K 0
#endif

// ---------------------------------------------------------------------------
// Kernel 0: W -> bf16, FRAG-ORDERED layout (unchanged, verified round 6-19).
// ---------------------------------------------------------------------------
__global__ __launch_bounds__(256) void wt_kernel(
    const float* __restrict__ Wq, const float* __restrict__ Wk,
    const float* __restrict__ Wv, u16* __restrict__ wt)
{
    const int flat = blockIdx.x * 256 + threadIdx.x;   // 0..196607
    const int mat = flat >> 16;
    const int within = flat & 65535;                   // = k*64 + h
    const int kk = within >> 6;
    const int h  = within & 63;
    const float* W = (mat == 0) ? Wq : (mat == 1) ? Wk : Wv;
    const int mh = mat * 4 + (h >> 4);
    const int lane = (((kk >> 3) & 3) << 4) | (h & 15);
    const long idx = (long)mh * 16384 + (long)(kk >> 5) * 512 + lane * 8 + (kk & 7);
    wt[idx] = f2b(W[within]);
}

// ---------------------------------------------------------------------------
// Kernel 1: QKV projection — EXACT round-8/13 kernel (fastest proj measured:
// ~33.5 us). 256 blocks x 4 waves x 16 rows = 64 rows/block; 16 E-chunks of
// 64. x-tile 16KB (XOR-16 swizzled via pre-swizzled source) + wt-slice 24KB
// (frag-ordered, linear) staged via global_load_lds; double buffered (80KB).
// 10 DMA ops/wave/stage -> counted vmcnt(10), raw s_barrier.
// ---------------------------------------------------------------------------
__global__ __launch_bounds__(256) void proj_kernel(
    const float* __restrict__ x, const u16* __restrict__ wt,
    const float* __restrict__ bq, const float* __restrict__ bk,
    const float* __restrict__ bv,
    u16* __restrict__ qs, u16* __restrict__ ks, u16* __restrict__ vt)
{
    __shared__ __align__(1024) char smem[81920];  // x: 2x16KB, wt: 2x24KB

    const int tid  = threadIdx.x;
    const int w    = tid >> 6;
    const int lane = tid & 63;
    const int l15 = lane & 15, g = lane >> 4;
    const long row0 = (long)blockIdx.x * 64;
    const char* xgb = (const char*)(x + row0 * E_DIM);
    const char* wgb = (const char*)wt;

    f32x4 zz = {0.f, 0.f, 0.f, 0.f};
    f32x4 o[12];
#pragma unroll
    for (int i = 0; i < 12; ++i) o[i] = zz;

#define XOFF(b) ((b) * 16384)
#define WOFF(b) (32768 + (b) * 24576)

#define PSTAGE(b, c) do {                                                     \
    _Pragma("unroll")                                                         \
    for (int ii = 0; ii < 4; ++ii) {                                          \
        const int i = w * 4 + ii;                                             \
        const int row = i * 4 + (lane >> 4);                                  \
        const int sslot = (lane & 15) ^ (row & 15);                           \
        gload16(xgb + (long)row * 4096 + (c) * 256 + (sslot << 4),            \
                smem + XOFF(b) + i * 1024);                                   \
    }                                                                         \
    _Pragma("unroll")                                                         \
    for (int j = 0; j < 6; ++j) {                                             \
        const int f = w * 6 + j;                                              \
        const int mh = f >> 1, ksl = f & 1;                                   \
        gload16(wgb + (long)mh * 32768 + ((c) * 2 + ksl) * 1024 + lane * 16,  \
                smem + WOFF(b) + f * 1024);                                   \
    }                                                                         \
} while (0)

#define PCOMP(b) do {                                                         \
    _Pragma("unroll")                                                         \
    for (int ksl = 0; ksl < 2; ++ksl) {                                       \
        const char* xrow = smem + XOFF(b) + (w * 16 + l15) * 256;             \
        const float4 fa = *(const float4*)(                                   \
            xrow + (((ksl * 8 + 2 * g) ^ l15) << 4));                         \
        const float4 fb = *(const float4*)(                                   \
            xrow + (((ksl * 8 + 2 * g + 1) ^ l15) << 4));                     \
        s16x8 xa;                                                             \
        xa[0] = (short)f2b(fa.x); xa[1] = (short)f2b(fa.y);                   \
        xa[2] = (short)f2b(fa.z); xa[3] = (short)f2b(fa.w);                   \
        xa[4] = (short)f2b(fb.x); xa[5] = (short)f2b(fb.y);                   \
        xa[6] = (short)f2b(fb.z); xa[7] = (short)f2b(fb.w);                   \
        _Pragma("unroll")                                                     \
        for (int mh = 0; mh < 12; ++mh) {                                     \
            const s16x8 wa = *(const s16x8*)(                                 \
                smem + WOFF(b) + (mh * 2 + ksl) * 1024 + lane * 16);          \
            o[mh] = __builtin_amdgcn_mfma_f32_16x16x32_bf16(wa, xa, o[mh],    \
                                                            0, 0, 0);         \
        }                                                                     \
    }                                                                         \
} while (0)

#define WAITV10() do { asm volatile("s_waitcnt vmcnt(10)" ::: "memory");      \
    __builtin_amdgcn_sched_barrier(0); } while (0)
#define WAITV0() do { asm volatile("s_waitcnt vmcnt(0)" ::: "memory");        \
    __builtin_amdgcn_sched_barrier(0); } while (0)
#define LGKM0() do { asm volatile("s_waitcnt lgkmcnt(0)" ::: "memory");       \
    __builtin_amdgcn_sched_barrier(0); } while (0)
#define BAR() do { __builtin_amdgcn_s_barrier();                              \
    __builtin_amdgcn_sched_barrier(0); } while (0)

    PSTAGE(0, 0);
    PSTAGE(1, 1);
#pragma unroll
    for (int c = 0; c < 16; ++c) {
        const int b = c & 1;
        if (c == 15) { WAITV0(); } else { WAITV10(); }
        BAR();
        PCOMP(b);
        if (c + 2 < 16) {
            LGKM0();
            BAR();
            PSTAGE(b, c + 2);
        }
    }
#undef PSTAGE
#undef PCOMP
#undef WAITV10
#undef WAITV0
#undef LGKM0
#undef BAR
#undef XOFF
#undef WOFF

    const long rg = row0 + w * 16 + l15;
    const int batch = (int)(rg >> 12);
    const int sl = (int)(rg & 4095);
#pragma unroll
    for (int mh = 0; mh < 12; ++mh) {
        const int mat = mh >> 2, hb = mh & 3;
        const float* bias = (mat == 0) ? bq : (mat == 1) ? bk : bv;
        const float4 bb = *(const float4*)(bias + hb * 16 + 4 * g);
        float r0 = o[mh][0] + bb.x, r1 = o[mh][1] + bb.y;
        float r2 = o[mh][2] + bb.z, r3 = o[mh][3] + bb.w;
        if (mat == 0) {
            r0 *= QSCALE; r1 *= QSCALE; r2 *= QSCALE; r3 *= QSCALE;
            uint2 pk; pk.x = pk2(r0, r1); pk.y = pk2(r2, r3);
            *(uint2*)(qs + rg * H_DIM + hb * 16 + 4 * g) = pk;
        } else if (mat == 1) {
            uint2 pk; pk.x = pk2(r0, r1); pk.y = pk2(r2, r3);
            *(uint2*)(ks + rg * H_DIM + hb * 16 + 4 * g) = pk;
        } else {
            const long hbase = (long)batch * H_DIM + hb * 16 + 4 * g;
            vt[(hbase + 0) * S_LEN + sl] = f2b(r0);
            vt[(hbase + 1) * S_LEN + sl] = f2b(r1);
            vt[(hbase + 2) * S_LEN + sl] = f2b(r2);
            vt[(hbase + 3) * S_LEN + sl] = f2b(r3);
        }
    }
}

// ---------------------------------------------------------------------------
// Kernel 2: LDS-staged split-K causal flash attention — EXACT round-17
// version (4-wave, fp16 partials; best measured attn stack).
// ---------------------------------------------------------------------------
__global__ __launch_bounds__(256) void attn_stage_kernel(
    const u16* __restrict__ q, const u16* __restrict__ k,
    const u16* __restrict__ vt, float* __restrict__ out,
    u16* __restrict__ partO, float* __restrict__ stats2, int mode)
{
    __shared__ __align__(1024) char smem[32768];   // 2 bufs x (8KB K + 8KB V)

    const int tid  = threadIdx.x;
    const int w    = tid >> 6;
    const int lane = tid & 63;
    const int l15 = lane & 15, g = lane >> 4;
    const int h7  = l15 & 7;
    const int bid = blockIdx.x;
    const int batch = bid & 3;
    const int r = bid >> 2;

    int qg, c;
    if (mode) {                          // prefix-decode r -> (qg, c)
        if      (r < 8)   { qg = r;                  c = 0;      }
        else if (r < 24)  { int rr = r - 8;   qg = 8  + rr / 2; c = rr % 2; }
        else if (r < 48)  { int rr = r - 24;  qg = 16 + rr / 3; c = rr % 3; }
        else if (r < 80)  { int rr = r - 48;  qg = 24 + rr / 4; c = rr % 4; }
        else if (r < 120) { int rr = r - 80;  qg = 32 + rr / 5; c = rr % 5; }
        else if (r < 168) { int rr = r - 120; qg = 40 + rr / 6; c = rr % 6; }
        else if (r < 224) { int rr = r - 168; qg = 48 + rr / 7; c = rr % 7; }
        else              { int rr = r - 224; qg = 56 + rr / 8; c = rr % 8; }
    } else { qg = r; c = 0; }

    const int chunk_sz = mode ? CHUNK : S_LEN;
    const int qt = 4 * qg + w;
    const int qw = qt * 16;
    const int k0 = c * CHUNK;
    const int kend = min(k0 + chunk_sz, qg * 64 + 64);
    const int T = (kend - k0 + KB - 1) >> 6;
    const bool active = (k0 <= qw + 15);

    const long base = (long)batch * S_LEN * H_DIM;
    const char* kg = (const char*)(k + base);
    const char* vg = (const char*)(vt + (long)batch * H_DIM * S_LEN);

    const u16* qrow = q + base + (long)(qw + l15) * H_DIM;
    const s16x8 qa0 = *(const s16x8*)(qrow + g * 8);
    const s16x8 qa1 = *(const s16x8*)(qrow + 32 + g * 8);

    f32x4 o[4];
    f32x4 zz = {0.f, 0.f, 0.f, 0.f};
#pragma unroll
    for (int cc = 0; cc < 4; ++cc) o[cc] = zz;
    float m = -INFINITY, lacc = 0.f;
    const int qglane = qw + l15;

    const int srow  = lane >> 3;
    const int sslot = (lane & 7) ^ srow;

#define STAGE(bufb, kv0_) do {                                               \
    char* kd = smem + (bufb) + 2048 * w;                                     \
    const long krw = (long)((kv0_) + 16 * w + srow);                         \
    gload16(kg + krw * 128 + (sslot << 4), kd);                              \
    gload16(kg + (krw + 8) * 128 + (sslot << 4), kd + 1024);                 \
    char* vd = smem + (bufb) + 8192 + 2048 * w;                              \
    const long vrw = (long)(16 * w + srow);                                  \
    const long vco = (long)(kv0_) * 2 + (sslot << 4);                        \
    gload16(vg + vrw * 8192 + vco, vd);                                      \
    gload16(vg + (vrw + 8) * 8192 + vco, vd + 1024);                         \
} while (0)

    STAGE(0, k0);
    __syncthreads();

    for (int t = 0; t < T; ++t) {
        const int cb  = (t & 1) << 14;
        const int kv0 = k0 + t * KB;
        if (t + 1 < T) STAGE(cb ^ 16384, kv0 + KB);

        if (active && kv0 <= qw + 15) {
            const char* Kb = smem + cb;
            const char* Vb = smem + cb + 8192;
            f32x4 st[4];
#pragma unroll
            for (int kt = 0; kt < 4; ++kt) {
                const int rb = (kt * 16 + l15) * 128;
                const s16x8 ka0 = *(const s16x8*)(Kb + rb + ((g ^ h7) << 4));
                const s16x8 ka1 = *(const s16x8*)(Kb + rb + (((4 + g) ^ h7) << 4));
                st[kt] = __builtin_amdgcn_mfma_f32_16x16x32_bf16(ka0, qa0, zz, 0, 0, 0);
                st[kt] = __builtin_amdgcn_mfma_f32_16x16x32_bf16(ka1, qa1, st[kt], 0, 0, 0);
            }
            float p[16];
            if (kv0 + KB - 1 > qw) {
#pragma unroll
                for (int kt = 0; kt < 4; ++kt)
#pragma unroll
                    for (int rr2 = 0; rr2 < 4; ++rr2)
                        p[kt * 4 + rr2] =
                            (kv0 + kt * 16 + 4 * g + rr2 <= qglane) ? st[kt][rr2] : -INFINITY;
            } else {
#pragma unroll
                for (int i = 0; i < 16; ++i) p[i] = st[i >> 2][i & 3];
            }
            float pm = p[0];
#pragma unroll
            for (int i = 1; i < 16; ++i) pm = fmaxf(pm, p[i]);
            pm = fmaxf(pm, __shfl_xor(pm, 16, 64));
            pm = fmaxf(pm, __shfl_xor(pm, 32, 64));
            const float mnew = fmaxf(m, pm);
            const float corr = exp2f(m - mnew);
            float psum = 0.f;
#pragma unroll
            for (int i = 0; i < 16; ++i) { p[i] = exp2f(p[i] - mnew); psum += p[i]; }
            psum += __shfl_xor(psum, 16, 64);
            psum += __shfl_xor(psum, 32, 64);
            lacc = lacc * corr + psum;
            m = mnew;
#pragma unroll
            for (int cc = 0; cc < 4; ++cc) {
                o[cc][0] *= corr; o[cc][1] *= corr; o[cc][2] *= corr; o[cc][3] *= corr;
            }
#if USE_1K
#pragma unroll
            for (int kt = 0; kt < 4; ++kt) {
                s16x4 pa;
                pa[0] = (short)f2b(p[kt * 4 + 0]); pa[1] = (short)f2b(p[kt * 4 + 1]);
                pa[2] = (short)f2b(p[kt * 4 + 2]); pa[3] = (short)f2b(p[kt * 4 + 3]);
                const int so = (((kt * 2 + (g >> 1)) ^ h7) << 4) + (g & 1) * 8;
#pragma unroll
                for (int cc = 0; cc < 4; ++cc) {
                    const s16x4 va = *(const s16x4*)(Vb + (cc * 16 + l15) * 128 + so);
                    o[cc] = __builtin_amdgcn_mfma_f32_16x16x16bf16_1k(va, pa, o[cc], 0, 0, 0);
                }
            }
#else
#pragma unroll
            for (int hh = 0; hh < 2; ++hh) {
                const u32 w0 = pk2(p[8*hh+0], p[8*hh+1]), w1 = pk2(p[8*hh+2], p[8*hh+3]);
                const u32 w2 = pk2(p[8*hh+4], p[8*hh+5]), w3 = pk2(p[8*hh+6], p[8*hh+7]);
                const int srcA = ((g & 1) * 2) * 16 + l15, srcB = srcA + 16;
                const u32 a0 = (u32)__shfl((int)w0, srcA, 64), a1 = (u32)__shfl((int)w1, srcA, 64);
                const u32 a2 = (u32)__shfl((int)w2, srcA, 64), a3 = (u32)__shfl((int)w3, srcA, 64);
                const u32 b0 = (u32)__shfl((int)w0, srcB, 64), b1 = (u32)__shfl((int)w1, srcB, 64);
                const u32 b2 = (u32)__shfl((int)w2, srcB, 64), b3 = (u32)__shfl((int)w3, srcB, 64);
                const bool losel = (g < 2);
                const u32 d0 = losel ? a0 : a2, d1 = losel ? a1 : a3;
                const u32 d2 = losel ? b0 : b2, d3 = losel ? b1 : b3;
                s16x8 pa;
                pa[0] = (short)(d0 & 0xffff); pa[1] = (short)(d0 >> 16);
                pa[2] = (short)(d1 & 0xffff); pa[3] = (short)(d1 >> 16);
                pa[4] = (short)(d2 & 0xffff); pa[5] = (short)(d2 >> 16);
                pa[6] = (short)(d3 & 0xffff); pa[7] = (short)(d3 >> 16);
                const int so = ((hh * 4 + g) ^ h7) << 4;
#pragma unroll
                for (int cc = 0; cc < 4; ++cc) {
                    const s16x8 va = *(const s16x8*)(Vb + (cc * 16 + l15) * 128 + so);
                    o[cc] = __builtin_amdgcn_mfma_f32_16x16x32_bf16(va, pa, o[cc], 0, 0, 0);
                }
            }
#endif
        }
        __syncthreads();
    }
#undef STAGE

    if (active) {
        if (mode) {
            const long slot = ((long)batch * 256 + qt) * MAXC + c;
            u16* pb = partO + (slot * 16 + l15) * 64;
#pragma unroll
            for (int cc = 0; cc < 4; ++cc) {
                uint2 pk;
                pk.x = pkh2(o[cc][0], o[cc][1]);
                pk.y = pkh2(o[cc][2], o[cc][3]);
                *(uint2*)(pb + cc * 16 + 4 * g) = pk;
            }
            if (lane < 16) {
                float2 s2; s2.x = m; s2.y = lacc;
                *(float2*)(stats2 + (slot * 16 + l15) * 2) = s2;
            }
        } else {
            const float inv = 1.0f / lacc;
            float* ob = out + base + (long)(qw + l15) * H_DIM;
#pragma unroll
            for (int cc = 0; cc < 4; ++cc) {
                float4 stv; stv.x = o[cc][0] * inv; stv.y = o[cc][1] * inv;
                stv.z = o[cc][2] * inv; stv.w = o[cc][3] * inv;
                *(float4*)(ob + cc * 16 + 4 * g) = stv;
            }
        }
    }
}

// ---------------------------------------------------------------------------
// Kernel 3: split-K combine (exp2 domain), fp16 partials. Exact round-17.
// ---------------------------------------------------------------------------
__global__ __launch_bounds__(256) void combine_kernel(
    const u16* __restrict__ partO, const float* __restrict__ stats2,
    float* __restrict__ out)
{
    const int wv   = threadIdx.x >> 6;
    const int lane = threadIdx.x & 63;
    const int l15 = lane & 15, g = lane >> 4;
    const int bid = blockIdx.x;
    const int batch = bid & 3;
    const int qt = (bid >> 2) * 4 + wv;
    const int nc = (qt * 16) / CHUNK + 1;

    f32x4 O[4];
    f32x4 zz = {0.f, 0.f, 0.f, 0.f};
#pragma unroll
    for (int i = 0; i < 4; ++i) O[i] = zz;
    float M = -INFINITY, L = 0.f;

    for (int c = 0; c < nc; ++c) {
        const long slot = ((long)batch * 256 + qt) * MAXC + c;
        const float2 s = *(const float2*)(stats2 + (slot * 16 + l15) * 2);
        const float Mn = fmaxf(M, s.x);
        const float a  = exp2f(M - Mn);
        const float bw = exp2f(s.x - Mn);
        const u16* pb = partO + (slot * 16 + l15) * 64 + g * 16;
#pragma unroll
        for (int i = 0; i < 4; ++i) {
            const uint2 d = *(const uint2*)(pb + 4 * i);
            f32x4 oc;
            oc[0] = h2f((u16)(d.x & 0xffff)); oc[1] = h2f((u16)(d.x >> 16));
            oc[2] = h2f((u16)(d.y & 0xffff)); oc[3] = h2f((u16)(d.y >> 16));
            O[i] = O[i] * a + oc * bw;
        }
        L = L * a + s.y * bw;
        M = Mn;
    }

    const float inv = 1.0f / L;
    float* ob = out + ((long)batch * S_LEN + qt * 16 + l15) * H_DIM + g * 16;
#pragma unroll
    for (int i = 0; i < 4; ++i) {
        float4 st; st.x = O[i][0] * inv; st.y = O[i][1] * inv;
        st.z = O[i][2] * inv; st.w = O[i][3] * inv;
        *(float4*)(ob + 4 * i) = st;
    }
}

// ---------------------------------------------------------------------------
extern "C" void kernel_launch(void* const* d_in, const int* in_sizes, int n_in,
                              void* d_out, int out_size, void* d_ws, size_t ws_size,
                              hipStream_t stream)
{
    const float* x  = (const float*)d_in[0];
    const float* Wq = (const float*)d_in[1];
    const float* bq = (const float*)d_in[2];
    const float* Wk = (const float*)d_in[3];
    const float* bk = (const float*)d_in[4];
    const float* Wv = (const float*)d_in[5];
    const float* bv = (const float*)d_in[6];
    float* out = (float*)d_out;

    const long BSH = (long)B_SZ * S_LEN * H_DIM;   // 1,048,576
    u16* qs = (u16*)d_ws;
    u16* ks = qs + BSH;
    u16* vt = ks + BSH;
    u16* wt = vt + BSH;                            // 192*1024 u16 (frag-ordered)

    // Partials at 8 MiB: fp16 partO (slots*16*64 u16) + fp32 stats.
    const size_t PART_OFF = (size_t)8 << 20;
    const size_t slots = (size_t)1024 * MAXC;
    const int split_ok = (PART_OFF + slots * (2048 + 128) <= ws_size);
    u16* partO   = (u16*)((char*)d_ws + PART_OFF);
    float* stats2 = (float*)(partO + slots * 1024);

    wt_kernel<<<768, 256, 0, stream>>>(Wq, Wk, Wv, wt);
    proj_kernel<<<B_SZ * S_LEN / 64, 256, 0, stream>>>(x, wt, bq, bk, bv, qs, ks, vt);
    if (split_ok) {
        attn_stage_kernel<<<1152, 256, 0, stream>>>(qs, ks, vt, out, partO, stats2, 1);
        combine_kernel<<<256, 256, 0, stream>>>(partO, stats2, out);
    } else {
        attn_stage_kernel<<<256, 256, 0, stream>>>(qs, ks, vt, out, partO, stats2, 0);
    }
}

// Round 21
// 68.666 us; speedup vs baseline: 1.0224x; 1.0224x over previous
//
#include <hip/hip_runtime.h>
#include <math.h>

#define E_DIM 1024
#define H_DIM 64
#define S_LEN 4096
#define B_SZ  4

typedef short s16x8 __attribute__((ext_vector_type(8)));
typedef short s16x4 __attribute__((ext_vector_type(4)));
typedef float f32x4 __attribute__((ext_vector_type(4)));
typedef unsigned short u16;
typedef unsigned int u32;

// q is pre-scaled by 1/sqrt(H) * log2(e) so attention uses exp2 throughout.
#define QSCALE 0.180336880f
#define CHUNK  512
#define MAXC   8      // S_LEN / CHUNK
#define KB     64     // keys per staged LDS tile (attention)

static __device__ __forceinline__ u16 f2b(float f) {
    u32 u = __builtin_bit_cast(u32, f);
    u += 0x7fffu + ((u >> 16) & 1u);        // RNE
    return (u16)(u >> 16);
}
static __device__ __forceinline__ u32 pk2(float lo, float hi) {
    return (u32)f2b(lo) | ((u32)f2b(hi) << 16);
}
// fp16 pack/unpack for attn split-K partials (|O_part| <~ 3e3 << 65504;
// post-division error ~2e-3 << 0.079 threshold).
static __device__ __forceinline__ u32 pkh2(float a, float b) {
    _Float16 ha = (_Float16)a, hb = (_Float16)b;
    return (u32)__builtin_bit_cast(u16, ha) | ((u32)__builtin_bit_cast(u16, hb) << 16);
}
static __device__ __forceinline__ float h2f(u16 u) {
    return (float)__builtin_bit_cast(_Float16, u);
}

// async global->LDS, 16B per lane; LDS dest = wave-uniform base + lane*16,
// global source is per-lane.
static __device__ __forceinline__ void gload16(const void* g, void* l) {
    __builtin_amdgcn_global_load_lds(
        (const __attribute__((address_space(1))) u32*)g,
        (__attribute__((address_space(3))) u32*)l, 16, 0, 0);
}

#if defined(__has_builtin)
#  if __has_builtin(__builtin_amdgcn_mfma_f32_16x16x16bf16_1k)
#    define USE_1K 1
#  else
#    define USE_1K 0
#  endif
#else
#  define USE_1K 0
#endif

// ---------------------------------------------------------------------------
// Kernel 0: W -> bf16, FRAG-ORDERED layout (verified rounds 6-20).
// ---------------------------------------------------------------------------
__global__ __launch_bounds__(256) void wt_kernel(
    const float* __restrict__ Wq, const float* __restrict__ Wk,
    const float* __restrict__ Wv, u16* __restrict__ wt)
{
    const int flat = blockIdx.x * 256 + threadIdx.x;   // 0..196607
    const int mat = flat >> 16;
    const int within = flat & 65535;                   // = k*64 + h
    const int kk = within >> 6;
    const int h  = within & 63;
    const float* W = (mat == 0) ? Wq : (mat == 1) ? Wk : Wv;
    const int mh = mat * 4 + (h >> 4);
    const int lane = (((kk >> 3) & 3) << 4) | (h & 15);
    const long idx = (long)mh * 16384 + (long)(kk >> 5) * 512 + lane * 8 + (kk & 7);
    wt[idx] = f2b(W[within]);
}

// ---------------------------------------------------------------------------
// Kernel 1: QKV projection — round-12/17 hybrid (best measured total).
// x -> global_load_lds into 2x8KB swizzled LDS tiles; wt -> direct-to-register
// coalesced dwordx4 (L2 path), double-buffered one phase ahead.
// 512 blocks x 4 waves (r2 = row-group of 16, ch = col-half of 6 mh);
// 16 K-phases of 64. Steady state s_waitcnt vmcnt(14).
// ---------------------------------------------------------------------------
__global__ __launch_bounds__(256) void proj_kernel(
    const float* __restrict__ x, const u16* __restrict__ wt,
    const float* __restrict__ bq, const float* __restrict__ bk,
    const float* __restrict__ bv,
    u16* __restrict__ qs, u16* __restrict__ ks, u16* __restrict__ vt)
{
    __shared__ __align__(1024) char smem[16384];  // 2 x 8KB x-tile

    const int tid  = threadIdx.x;
    const int wv   = tid >> 6;
    const int r2   = wv & 1;            // row-group: rows r2*16..+15
    const int ch   = wv >> 1;           // col-half: mh = ch*6..+5
    const int lane = tid & 63;
    const int l15 = lane & 15, g = lane >> 4;

    const long row0 = (long)blockIdx.x * 32;
    const char* xgb = (const char*)(x + row0 * E_DIM);
    const char* wgb = (const char*)wt;

    f32x4 zz = {0.f, 0.f, 0.f, 0.f};
    f32x4 o[6];
#pragma unroll
    for (int i = 0; i < 6; ++i) o[i] = zz;

    s16x8 wtA[12], wtB[12];   // [j*2+ksl]; compile-time indexed only

#define XSTAGE(b, c) do {                                                     \
    _Pragma("unroll")                                                         \
    for (int i = 0; i < 2; ++i) {                                             \
        const int row = wv * 8 + i * 4 + (lane >> 4);                         \
        const int sslot = (lane & 15) ^ (row & 15);                           \
        gload16(xgb + (long)row * 4096 + (c) * 256 + (sslot << 4),            \
                smem + (b) * 8192 + (wv * 2 + i) * 1024);                     \
    }                                                                         \
} while (0)

#define WTLOAD(W, c) do {                                                     \
    _Pragma("unroll")                                                         \
    for (int j = 0; j < 6; ++j) {                                             \
        _Pragma("unroll")                                                     \
        for (int ksl = 0; ksl < 2; ++ksl)                                     \
            W[j * 2 + ksl] = *(const s16x8*)(                                 \
                wgb + (long)(ch * 6 + j) * 32768 +                            \
                ((c) * 2 + ksl) * 1024 + lane * 16);                          \
    }                                                                         \
} while (0)

#define PCOMP(b, W) do {                                                      \
    const int rr = r2 * 16 + l15;                                             \
    const char* xrow = smem + (b) * 8192 + rr * 256;                          \
    _Pragma("unroll")                                                         \
    for (int ksl = 0; ksl < 2; ++ksl) {                                       \
        const float4 fa = *(const float4*)(                                   \
            xrow + (((ksl * 8 + 2 * g)     ^ l15) << 4));                     \
        const float4 fb = *(const float4*)(                                   \
            xrow + (((ksl * 8 + 2 * g + 1) ^ l15) << 4));                     \
        s16x8 xa;                                                             \
        xa[0] = (short)f2b(fa.x); xa[1] = (short)f2b(fa.y);                   \
        xa[2] = (short)f2b(fa.z); xa[3] = (short)f2b(fa.w);                   \
        xa[4] = (short)f2b(fb.x); xa[5] = (short)f2b(fb.y);                   \
        xa[6] = (short)f2b(fb.z); xa[7] = (short)f2b(fb.w);                   \
        _Pragma("unroll")                                                     \
        for (int j = 0; j < 6; ++j)                                           \
            o[j] = __builtin_amdgcn_mfma_f32_16x16x32_bf16(                   \
                W[j * 2 + ksl], xa, o[j], 0, 0, 0);                           \
    }                                                                         \
} while (0)

#define WAITV14() do { asm volatile("s_waitcnt vmcnt(14)" ::: "memory");      \
    __builtin_amdgcn_sched_barrier(0); } while (0)
#define WAITV0() do { asm volatile("s_waitcnt vmcnt(0)" ::: "memory");        \
    __builtin_amdgcn_sched_barrier(0); } while (0)
#define LGKM0() do { asm volatile("s_waitcnt lgkmcnt(0)" ::: "memory");       \
    __builtin_amdgcn_sched_barrier(0); } while (0)
#define BAR() do { __builtin_amdgcn_s_barrier();                              \
    __builtin_amdgcn_sched_barrier(0); } while (0)

    XSTAGE(0, 0);
    XSTAGE(1, 1);
    WTLOAD(wtA, 0);
#pragma unroll
    for (int c = 0; c < 16; ++c) {
        const int b = c & 1;
        if (c + 1 < 16) {
            if (b) WTLOAD(wtA, c + 1); else WTLOAD(wtB, c + 1);
        }
        if (c == 15) { WAITV0(); } else { WAITV14(); }
        BAR();
        if (b) PCOMP(b, wtB); else PCOMP(b, wtA);
        if (c + 2 < 16) {
            LGKM0();
            BAR();
            XSTAGE(b, c + 2);
        }
    }
#undef XSTAGE
#undef WTLOAD
#undef PCOMP
#undef WAITV14
#undef WAITV0
#undef LGKM0
#undef BAR

    const long rg = row0 + r2 * 16 + l15;
    const int batch = (int)(rg >> 12);
    const int sl = (int)(rg & 4095);
#pragma unroll
    for (int j = 0; j < 6; ++j) {
        const int mh = ch * 6 + j;
        const int mat = mh >> 2, hb = mh & 3;
        const float* bias = (mat == 0) ? bq : (mat == 1) ? bk : bv;
        const float4 bb = *(const float4*)(bias + hb * 16 + 4 * g);
        float r0 = o[j][0] + bb.x, r1 = o[j][1] + bb.y;
        float r2f = o[j][2] + bb.z, r3f = o[j][3] + bb.w;
        if (mat == 0) {
            r0 *= QSCALE; r1 *= QSCALE; r2f *= QSCALE; r3f *= QSCALE;
            uint2 pk; pk.x = pk2(r0, r1); pk.y = pk2(r2f, r3f);
            *(uint2*)(qs + rg * H_DIM + hb * 16 + 4 * g) = pk;
        } else if (mat == 1) {
            uint2 pk; pk.x = pk2(r0, r1); pk.y = pk2(r2f, r3f);
            *(uint2*)(ks + rg * H_DIM + hb * 16 + 4 * g) = pk;
        } else {
            const long hbase = (long)batch * H_DIM + hb * 16 + 4 * g;
            vt[(hbase + 0) * S_LEN + sl] = f2b(r0);
            vt[(hbase + 1) * S_LEN + sl] = f2b(r1);
            vt[(hbase + 2) * S_LEN + sl] = f2b(r2f);
            vt[(hbase + 3) * S_LEN + sl] = f2b(r3f);
        }
    }
}

// ---------------------------------------------------------------------------
// Kernel 2: LDS-staged split-K causal flash attention — round-17 version
// (4-wave, fp16 partials).
// ---------------------------------------------------------------------------
__global__ __launch_bounds__(256) void attn_stage_kernel(
    const u16* __restrict__ q, const u16* __restrict__ k,
    const u16* __restrict__ vt, float* __restrict__ out,
    u16* __restrict__ partO, float* __restrict__ stats2, int mode)
{
    __shared__ __align__(1024) char smem[32768];   // 2 bufs x (8KB K + 8KB V)

    const int tid  = threadIdx.x;
    const int w    = tid >> 6;
    const int lane = tid & 63;
    const int l15 = lane & 15, g = lane >> 4;
    const int h7  = l15 & 7;
    const int bid = blockIdx.x;
    const int batch = bid & 3;
    const int r = bid >> 2;

    int qg, c;
    if (mode) {                          // prefix-decode r -> (qg, c)
        if      (r < 8)   { qg = r;                  c = 0;      }
        else if (r < 24)  { int rr = r - 8;   qg = 8  + rr / 2; c = rr % 2; }
        else if (r < 48)  { int rr = r - 24;  qg = 16 + rr / 3; c = rr % 3; }
        else if (r < 80)  { int rr = r - 48;  qg = 24 + rr / 4; c = rr % 4; }
        else if (r < 120) { int rr = r - 80;  qg = 32 + rr / 5; c = rr % 5; }
        else if (r < 168) { int rr = r - 120; qg = 40 + rr / 6; c = rr % 6; }
        else if (r < 224) { int rr = r - 168; qg = 48 + rr / 7; c = rr % 7; }
        else              { int rr = r - 224; qg = 56 + rr / 8; c = rr % 8; }
    } else { qg = r; c = 0; }

    const int chunk_sz = mode ? CHUNK : S_LEN;
    const int qt = 4 * qg + w;
    const int qw = qt * 16;
    const int k0 = c * CHUNK;
    const int kend = min(k0 + chunk_sz, qg * 64 + 64);
    const int T = (kend - k0 + KB - 1) >> 6;
    const bool active = (k0 <= qw + 15);

    const long base = (long)batch * S_LEN * H_DIM;
    const char* kg = (const char*)(k + base);
    const char* vg = (const char*)(vt + (long)batch * H_DIM * S_LEN);

    const u16* qrow = q + base + (long)(qw + l15) * H_DIM;
    const s16x8 qa0 = *(const s16x8*)(qrow + g * 8);
    const s16x8 qa1 = *(const s16x8*)(qrow + 32 + g * 8);

    f32x4 o[4];
    f32x4 zz = {0.f, 0.f, 0.f, 0.f};
#pragma unroll
    for (int cc = 0; cc < 4; ++cc) o[cc] = zz;
    float m = -INFINITY, lacc = 0.f;
    const int qglane = qw + l15;

    const int srow  = lane >> 3;
    const int sslot = (lane & 7) ^ srow;

#define STAGE(bufb, kv0_) do {                                               \
    char* kd = smem + (bufb) + 2048 * w;                                     \
    const long krw = (long)((kv0_) + 16 * w + srow);                         \
    gload16(kg + krw * 128 + (sslot << 4), kd);                              \
    gload16(kg + (krw + 8) * 128 + (sslot << 4), kd + 1024);                 \
    char* vd = smem + (bufb) + 8192 + 2048 * w;                              \
    const long vrw = (long)(16 * w + srow);                                  \
    const long vco = (long)(kv0_) * 2 + (sslot << 4);                        \
    gload16(vg + vrw * 8192 + vco, vd);                                      \
    gload16(vg + (vrw + 8) * 8192 + vco, vd + 1024);                         \
} while (0)

    STAGE(0, k0);
    __syncthreads();

    for (int t = 0; t < T; ++t) {
        const int cb  = (t & 1) << 14;
        const int kv0 = k0 + t * KB;
        if (t + 1 < T) STAGE(cb ^ 16384, kv0 + KB);

        if (active && kv0 <= qw + 15) {
            const char* Kb = smem + cb;
            const char* Vb = smem + cb + 8192;
            f32x4 st[4];
#pragma unroll
            for (int kt = 0; kt < 4; ++kt) {
                const int rb = (kt * 16 + l15) * 128;
                const s16x8 ka0 = *(const s16x8*)(Kb + rb + ((g ^ h7) << 4));
                const s16x8 ka1 = *(const s16x8*)(Kb + rb + (((4 + g) ^ h7) << 4));
                st[kt] = __builtin_amdgcn_mfma_f32_16x16x32_bf16(ka0, qa0, zz, 0, 0, 0);
                st[kt] = __builtin_amdgcn_mfma_f32_16x16x32_bf16(ka1, qa1, st[kt], 0, 0, 0);
            }
            float p[16];
            if (kv0 + KB - 1 > qw) {
#pragma unroll
                for (int kt = 0; kt < 4; ++kt)
#pragma unroll
                    for (int rr2 = 0; rr2 < 4; ++rr2)
                        p[kt * 4 + rr2] =
                            (kv0 + kt * 16 + 4 * g + rr2 <= qglane) ? st[kt][rr2] : -INFINITY;
            } else {
#pragma unroll
                for (int i = 0; i < 16; ++i) p[i] = st[i >> 2][i & 3];
            }
            float pm = p[0];
#pragma unroll
            for (int i = 1; i < 16; ++i) pm = fmaxf(pm, p[i]);
            pm = fmaxf(pm, __shfl_xor(pm, 16, 64));
            pm = fmaxf(pm, __shfl_xor(pm, 32, 64));
            const float mnew = fmaxf(m, pm);
            const float corr = exp2f(m - mnew);
            float psum = 0.f;
#pragma unroll
            for (int i = 0; i < 16; ++i) { p[i] = exp2f(p[i] - mnew); psum += p[i]; }
            psum += __shfl_xor(psum, 16, 64);
            psum += __shfl_xor(psum, 32, 64);
            lacc = lacc * corr + psum;
            m = mnew;
#pragma unroll
            for (int cc = 0; cc < 4; ++cc) {
                o[cc][0] *= corr; o[cc][1] *= corr; o[cc][2] *= corr; o[cc][3] *= corr;
            }
#if USE_1K
#pragma unroll
            for (int kt = 0; kt < 4; ++kt) {
                s16x4 pa;
                pa[0] = (short)f2b(p[kt * 4 + 0]); pa[1] = (short)f2b(p[kt * 4 + 1]);
                pa[2] = (short)f2b(p[kt * 4 + 2]); pa[3] = (short)f2b(p[kt * 4 + 3]);
                const int so = (((kt * 2 + (g >> 1)) ^ h7) << 4) + (g & 1) * 8;
#pragma unroll
                for (int cc = 0; cc < 4; ++cc) {
                    const s16x4 va = *(const s16x4*)(Vb + (cc * 16 + l15) * 128 + so);
                    o[cc] = __builtin_amdgcn_mfma_f32_16x16x16bf16_1k(va, pa, o[cc], 0, 0, 0);
                }
            }
#else
#pragma unroll
            for (int hh = 0; hh < 2; ++hh) {
                const u32 w0 = pk2(p[8*hh+0], p[8*hh+1]), w1 = pk2(p[8*hh+2], p[8*hh+3]);
                const u32 w2 = pk2(p[8*hh+4], p[8*hh+5]), w3 = pk2(p[8*hh+6], p[8*hh+7]);
                const int srcA = ((g & 1) * 2) * 16 + l15, srcB = srcA + 16;
                const u32 a0 = (u32)__shfl((int)w0, srcA, 64), a1 = (u32)__shfl((int)w1, srcA, 64);
                const u32 a2 = (u32)__shfl((int)w2, srcA, 64), a3 = (u32)__shfl((int)w3, srcA, 64);
                const u32 b0 = (u32)__shfl((int)w0, srcB, 64), b1 = (u32)__shfl((int)w1, srcB, 64);
                const u32 b2 = (u32)__shfl((int)w2, srcB, 64), b3 = (u32)__shfl((int)w3, srcB, 64);
                const bool losel = (g < 2);
                const u32 d0 = losel ? a0 : a2, d1 = losel ? a1 : a3;
                const u32 d2 = losel ? b0 : b2, d3 = losel ? b1 : b3;
                s16x8 pa;
                pa[0] = (short)(d0 & 0xffff); pa[1] = (short)(d0 >> 16);
                pa[2] = (short)(d1 & 0xffff); pa[3] = (short)(d1 >> 16);
                pa[4] = (short)(d2 & 0xffff); pa[5] = (short)(d2 >> 16);
                pa[6] = (short)(d3 & 0xffff); pa[7] = (short)(d3 >> 16);
                const int so = ((hh * 4 + g) ^ h7) << 4;
#pragma unroll
                for (int cc = 0; cc < 4; ++cc) {
                    const s16x8 va = *(const s16x8*)(Vb + (cc * 16 + l15) * 128 + so);
                    o[cc] = __builtin_amdgcn_mfma_f32_16x16x32_bf16(va, pa, o[cc], 0, 0, 0);
                }
            }
#endif
        }
        __syncthreads();
    }
#undef STAGE

    if (active) {
        if (mode) {
            const long slot = ((long)batch * 256 + qt) * MAXC + c;
            u16* pb = partO + (slot * 16 + l15) * 64;
#pragma unroll
            for (int cc = 0; cc < 4; ++cc) {
                uint2 pk;
                pk.x = pkh2(o[cc][0], o[cc][1]);
                pk.y = pkh2(o[cc][2], o[cc][3]);
                *(uint2*)(pb + cc * 16 + 4 * g) = pk;
            }
            if (lane < 16) {
                float2 s2; s2.x = m; s2.y = lacc;
                *(float2*)(stats2 + (slot * 16 + l15) * 2) = s2;
            }
        } else {
            const float inv = 1.0f / lacc;
            float* ob = out + base + (long)(qw + l15) * H_DIM;
#pragma unroll
            for (int cc = 0; cc < 4; ++cc) {
                float4 stv; stv.x = o[cc][0] * inv; stv.y = o[cc][1] * inv;
                stv.z = o[cc][2] * inv; stv.w = o[cc][3] * inv;
                *(float4*)(ob + cc * 16 + 4 * g) = stv;
            }
        }
    }
}

// ---------------------------------------------------------------------------
// Kernel 3: split-K combine (exp2 domain), fp16 partials.
// ---------------------------------------------------------------------------
__global__ __launch_bounds__(256) void combine_kernel(
    const u16* __restrict__ partO, const float* __restrict__ stats2,
    float* __restrict__ out)
{
    const int wv   = threadIdx.x >> 6;
    const int lane = threadIdx.x & 63;
    const int l15 = lane & 15, g = lane >> 4;
    const int bid = blockIdx.x;
    const int batch = bid & 3;
    const int qt = (bid >> 2) * 4 + wv;
    const int nc = (qt * 16) / CHUNK + 1;

    f32x4 O[4];
    f32x4 zz = {0.f, 0.f, 0.f, 0.f};
#pragma unroll
    for (int i = 0; i < 4; ++i) O[i] = zz;
    float M = -INFINITY, L = 0.f;

    for (int c = 0; c < nc; ++c) {
        const long slot = ((long)batch * 256 + qt) * MAXC + c;
        const float2 s = *(const float2*)(stats2 + (slot * 16 + l15) * 2);
        const float Mn = fmaxf(M, s.x);
        const float a  = exp2f(M - Mn);
        const float bw = exp2f(s.x - Mn);
        const u16* pb = partO + (slot * 16 + l15) * 64 + g * 16;
#pragma unroll
        for (int i = 0; i < 4; ++i) {
            const uint2 d = *(const uint2*)(pb + 4 * i);
            f32x4 oc;
            oc[0] = h2f((u16)(d.x & 0xffff)); oc[1] = h2f((u16)(d.x >> 16));
            oc[2] = h2f((u16)(d.y & 0xffff)); oc[3] = h2f((u16)(d.y >> 16));
            O[i] = O[i] * a + oc * bw;
        }
        L = L * a + s.y * bw;
        M = Mn;
    }

    const float inv = 1.0f / L;
    float* ob = out + ((long)batch * S_LEN + qt * 16 + l15) * H_DIM + g * 16;
#pragma unroll
    for (int i = 0; i < 4; ++i) {
        float4 st; st.x = O[i][0] * inv; st.y = O[i][1] * inv;
        st.z = O[i][2] * inv; st.w = O[i][3] * inv;
        *(float4*)(ob + 4 * i) = st;
    }
}

// ---------------------------------------------------------------------------
extern "C" void kernel_launch(void* const* d_in, const int* in_sizes, int n_in,
                              void* d_out, int out_size, void* d_ws, size_t ws_size,
                              hipStream_t stream)
{
    const float* x  = (const float*)d_in[0];
    const float* Wq = (const float*)d_in[1];
    const float* bq = (const float*)d_in[2];
    const float* Wk = (const float*)d_in[3];
    const float* bk = (const float*)d_in[4];
    const float* Wv = (const float*)d_in[5];
    const float* bv = (const float*)d_in[6];
    float* out = (float*)d_out;

    const long BSH = (long)B_SZ * S_LEN * H_DIM;   // 1,048,576
    u16* qs = (u16*)d_ws;
    u16* ks = qs + BSH;
    u16* vt = ks + BSH;
    u16* wt = vt + BSH;                            // 192*1024 u16 (frag-ordered)

    // Partials at 8 MiB: fp16 partO (slots*16*64 u16) + fp32 stats.
    const size_t PART_OFF = (size_t)8 << 20;
    const size_t slots = (size_t)1024 * MAXC;
    const int split_ok = (PART_OFF + slots * (2048 + 128) <= ws_size);
    u16* partO   = (u16*)((char*)d_ws + PART_OFF);
    float* stats2 = (float*)(partO + slots * 1024);

    wt_kernel<<<768, 256, 0, stream>>>(Wq, Wk, Wv, wt);
    proj_kernel<<<B_SZ * S_LEN / 32, 256, 0, stream>>>(x, wt, bq, bk, bv, qs, ks, vt);
    if (split_ok) {
        attn_stage_kernel<<<1152, 256, 0, stream>>>(qs, ks, vt, out, partO, stats2, 1);
        combine_kernel<<<256, 256, 0, stream>>>(partO, stats2, out);
    } else {
        attn_stage_kernel<<<256, 256, 0, stream>>>(qs, ks, vt, out, partO, stats2, 0);
    }
}